// Round 1
// baseline (96.071 us; speedup 1.0000x reference)
//
#include <hip/hip_runtime.h>

// Gated CRF 3D→2D loss on MI355X.
// Shapes: y_hat (N=2, C=2, H=64, W=64, D=64) f32, sample (2,1,64,64,64) f32.
// Depth folds into batch (b = n*D+d); lane index = d gives stride-1 coalescing
// on every gather (innermost axis of the NCHWD layout is d).
// Loss = (sum_k - sum(k * <y_n, y_c>)) / (N*D*H*W), 7x7 window, center zeroed,
// zero-padded FEATURES (so OOB neighbors still contribute exp(-0.5*|f_c|^2) to sum_k).

constexpr int N = 2, C = 2, H = 64, W = 64, D = 64, R = 3;
constexpr int WD  = W * D;        // 4096
constexpr int HWD = H * W * D;    // 262144
constexpr float INV_SXY  = 1.0f / 6.0f;
constexpr float INV_SIMG = 10.0f; // 1/0.1

__global__ __launch_bounds__(256) void crf_loss_kernel(
    const float* __restrict__ y,   // (N,C,H,W,D)
    const float* __restrict__ s,   // (N,1,H,W,D)
    float* __restrict__ acc) {
    const int tid  = threadIdx.x;
    const int d    = tid & 63;          // lane = depth (stride-1)
    const int wsub = tid >> 6;          // wave id in block = w offset
    const int bid  = blockIdx.x;
    const int w = ((bid & 15) << 2) + wsub;
    const int h = (bid >> 4) & 63;
    const int n = bid >> 10;

    const float* yb = y + (size_t)n * (C * HWD) + d;  // + c*HWD + h*WD + w*D
    const float* sb = s + (size_t)n * HWD + d;        // + h*WD + w*D

    const int cidx = h * WD + w * D;
    const float sc  = sb[cidx];
    const float y0c = yb[cidx];
    const float y1c = yb[HWD + cidx];

    float sumk = 0.0f, sumprod = 0.0f;
    int oob = 0;

    #pragma unroll
    for (int di = -R; di <= R; ++di) {
        const int hh = h + di;
        const bool rowok = ((unsigned)hh < (unsigned)H);
        #pragma unroll
        for (int dj = -R; dj <= R; ++dj) {
            if (di == 0 && dj == 0) continue;
            const int ww = w + dj;
            if (rowok && ((unsigned)ww < (unsigned)W)) {
                const int idx = hh * WD + ww * D;
                const float sn = sb[idx];
                const float ds = (sn - sc) * INV_SIMG;
                const float dist2 =
                    (float)(di * di + dj * dj) * (INV_SXY * INV_SXY) + ds * ds;
                const float k = __expf(-0.5f * dist2);
                const float y0n = yb[idx];
                const float y1n = yb[HWD + idx];
                sumk    += k;
                sumprod += k * (y0n * y0c + y1n * y1c);
            } else {
                ++oob;  // zero-padded features: all OOB offsets share one k value
            }
        }
    }
    if (oob) {
        const float fh = (float)h * INV_SXY;
        const float fw = (float)w * INV_SXY;
        const float fs = sc * INV_SIMG;
        sumk += (float)oob * __expf(-0.5f * (fh * fh + fw * fw + fs * fs));
    }

    float part = sumk - sumprod;

    // wave (64-lane) shuffle reduction
    #pragma unroll
    for (int off = 32; off; off >>= 1)
        part += __shfl_down(part, off, 64);

    __shared__ float wsum[4];
    if ((tid & 63) == 0) wsum[tid >> 6] = part;
    __syncthreads();
    if (tid == 0) {
        atomicAdd(acc, wsum[0] + wsum[1] + wsum[2] + wsum[3]);
    }
}

__global__ void finalize_kernel(const float* __restrict__ acc,
                                float* __restrict__ out) {
    out[0] = acc[0] * (1.0f / (float)(N * D * H * W));
}

extern "C" void kernel_launch(void* const* d_in, const int* in_sizes, int n_in,
                              void* d_out, int out_size, void* d_ws, size_t ws_size,
                              hipStream_t stream) {
    const float* y = (const float*)d_in[0];   // y_hat_softmax
    const float* s = (const float*)d_in[1];   // sample
    float* acc = (float*)d_ws;                // 4-byte accumulator in workspace

    hipMemsetAsync(acc, 0, sizeof(float), stream);  // ws is poisoned 0xAA each call
    crf_loss_kernel<<<dim3(2 * 64 * 16), dim3(256), 0, stream>>>(y, s, acc);
    finalize_kernel<<<dim3(1), dim3(1), 0, stream>>>(acc, (float*)d_out);
}

// Round 2
// 74.596 us; speedup vs baseline: 1.2879x; 1.2879x over previous
//
#include <hip/hip_runtime.h>

// Gated CRF 3D->2D loss, round 2: float4 over depth.
// One thread = (n, h, w, d0..d0+3). Lane group of 16 threads covers all 64 d
// contiguously (16 lanes x 16 B = 256 B), 4 w per wave -> 1 KB coalesced
// wave-loads. 4x fewer load issues, 4x ILP vs round 1 (which was
// latency-bound: VALUBusy 26%, VGPR 16).

constexpr int N = 2, C = 2, H = 64, W = 64, D = 64, R = 3;
constexpr int WD  = W * D;        // 4096
constexpr int HWD = H * W * D;    // 262144
constexpr float INV_SXY  = 1.0f / 6.0f;
constexpr float INV_SIMG = 10.0f;
constexpr int NBLOCKS = N * H * (W / 16);   // 512 partial blocks

__global__ __launch_bounds__(256) void crf_partial(
    const float* __restrict__ y,   // (N,C,H,W,D)
    const float* __restrict__ s,   // (N,1,H,W,D)
    float* __restrict__ partial) { // NBLOCKS slots in d_ws
    const int tid   = threadIdx.x;
    const int d0    = (tid & 15) << 2;     // depth quad, 16B aligned
    const int wlane = tid >> 4;            // 0..15
    const int bid   = blockIdx.x;
    const int w = ((bid & 3) << 4) + wlane;
    const int h = (bid >> 2) & 63;
    const int n = bid >> 8;

    const float* sb  = s + (size_t)n * HWD;
    const float* y0b = y + (size_t)n * (C * HWD);
    const float* y1b = y0b + HWD;

    const int cidx = h * WD + w * D + d0;
    const float4 sc4  = *(const float4*)(sb  + cidx);
    const float4 y0c4 = *(const float4*)(y0b + cidx);
    const float4 y1c4 = *(const float4*)(y1b + cidx);
    const float scv[4]  = {sc4.x,  sc4.y,  sc4.z,  sc4.w};
    const float y0cv[4] = {y0c4.x, y0c4.y, y0c4.z, y0c4.w};
    const float y1cv[4] = {y1c4.x, y1c4.y, y1c4.z, y1c4.w};

    float sumk = 0.0f, sumprod = 0.0f;
    int oob = 0;

    #pragma unroll
    for (int di = -R; di <= R; ++di) {
        const int hh = h + di;
        const bool rowok = ((unsigned)hh < (unsigned)H);
        #pragma unroll
        for (int dj = -R; dj <= R; ++dj) {
            if (di == 0 && dj == 0) continue;
            const int ww = w + dj;
            if (rowok && ((unsigned)ww < (unsigned)W)) {
                const int idx = hh * WD + ww * D + d0;
                const float4 sn4  = *(const float4*)(sb  + idx);
                const float4 y0n4 = *(const float4*)(y0b + idx);
                const float4 y1n4 = *(const float4*)(y1b + idx);
                const float dxy2 =
                    (float)(di * di + dj * dj) * (INV_SXY * INV_SXY);
                const float snv[4]  = {sn4.x,  sn4.y,  sn4.z,  sn4.w};
                const float y0nv[4] = {y0n4.x, y0n4.y, y0n4.z, y0n4.w};
                const float y1nv[4] = {y1n4.x, y1n4.y, y1n4.z, y1n4.w};
                #pragma unroll
                for (int j = 0; j < 4; ++j) {
                    const float ds = (snv[j] - scv[j]) * INV_SIMG;
                    const float k  = __expf(-0.5f * (dxy2 + ds * ds));
                    sumk    += k;
                    sumprod += k * (y0nv[j] * y0cv[j] + y1nv[j] * y1cv[j]);
                }
            } else {
                ++oob;  // zero-padded features: one shared k per OOB offset
            }
        }
    }
    if (oob) {
        const float fh = (float)h * INV_SXY;
        const float fw = (float)w * INV_SXY;
        const float base = fh * fh + fw * fw;
        float koob = 0.0f;
        #pragma unroll
        for (int j = 0; j < 4; ++j) {
            const float fs = scv[j] * INV_SIMG;
            koob += __expf(-0.5f * (base + fs * fs));
        }
        sumk += (float)oob * koob;
    }

    float part = sumk - sumprod;
    #pragma unroll
    for (int off = 32; off; off >>= 1)
        part += __shfl_down(part, off, 64);

    __shared__ float wsum[4];
    if ((tid & 63) == 0) wsum[tid >> 6] = part;
    __syncthreads();
    if (tid == 0) partial[bid] = wsum[0] + wsum[1] + wsum[2] + wsum[3];
}

__global__ __launch_bounds__(256) void reduce_partials(
    const float* __restrict__ partial, float* __restrict__ out) {
    const int tid = threadIdx.x;
    float v = partial[tid] + partial[tid + 256];   // NBLOCKS = 512
    #pragma unroll
    for (int off = 32; off; off >>= 1)
        v += __shfl_down(v, off, 64);
    __shared__ float wsum[4];
    if ((tid & 63) == 0) wsum[tid >> 6] = v;
    __syncthreads();
    if (tid == 0)
        out[0] = (wsum[0] + wsum[1] + wsum[2] + wsum[3]) *
                 (1.0f / (float)(N * D * H * W));
}

extern "C" void kernel_launch(void* const* d_in, const int* in_sizes, int n_in,
                              void* d_out, int out_size, void* d_ws, size_t ws_size,
                              hipStream_t stream) {
    const float* y = (const float*)d_in[0];
    const float* s = (const float*)d_in[1];
    float* partial = (float*)d_ws;   // 512 floats; every slot written, no init

    crf_partial<<<dim3(NBLOCKS), dim3(256), 0, stream>>>(y, s, partial);
    reduce_partials<<<dim3(1), dim3(256), 0, stream>>>(partial, (float*)d_out);
}

// Round 3
// 65.264 us; speedup vs baseline: 1.4720x; 1.1430x over previous
//
#include <hip/hip_runtime.h>

// Gated CRF 3D->2D loss, round 3: pair symmetry + C=2 softmax identity.
//   loss = sum_{c,n} k(c,n) * (1 - <y_n, y_c>) / (NB*H*W)
// k and <,> are symmetric -> compute each interior pair once (24 half-window
// offsets), double it. With C=2 softmax, y1 = 1-y0 exactly, so
// 1 - <y_n,y_c> = a + b - 2ab  (a=y0_n, b=y0_c): only channel 0 is loaded.
// OOB (zero-padded features): each OOB offset of center c contributes
// exp(-0.5|f_c|^2); count = 49 - nrows*ncols, closed form.
// One thread = (n, h, w, depth-quad) with float4 depth loads (R2's layout).

constexpr int N = 2, H = 64, W = 64, D = 64, R = 3;
constexpr int WD  = W * D;        // 4096
constexpr int HWD = H * W * D;    // 262144
constexpr float INV_SXY  = 1.0f / 6.0f;
constexpr float INV_SIMG = 10.0f;
constexpr int NBLOCKS = N * H * (W / 16);   // 512

__global__ __launch_bounds__(256) void crf_partial(
    const float* __restrict__ y,   // (N,2,H,W,D) -- only channel 0 read
    const float* __restrict__ s,   // (N,1,H,W,D)
    float* __restrict__ partial) {
    const int tid   = threadIdx.x;
    const int d0    = (tid & 15) << 2;     // depth quad (16B aligned)
    const int wlane = tid >> 4;
    const int bid   = blockIdx.x;
    const int w = ((bid & 3) << 4) + wlane;
    const int h = (bid >> 2) & 63;
    const int n = bid >> 8;

    const float* sb  = s + (size_t)n * HWD;
    const float* y0b = y + (size_t)n * (2 * HWD);   // channel 0

    const int cidx = h * WD + w * D + d0;
    const float4 sc4 = *(const float4*)(sb  + cidx);
    const float4 b4  = *(const float4*)(y0b + cidx);
    const float scv[4] = {sc4.x, sc4.y, sc4.z, sc4.w};
    const float bv[4]  = {b4.x,  b4.y,  b4.z,  b4.w};

    float acc[4] = {0.f, 0.f, 0.f, 0.f};

    // 24 half-window pair offsets: (0,1..3) and (1..3, -3..3)
    #pragma unroll
    for (int di = 0; di <= R; ++di) {
        const int hh = h + di;
        const bool rowok = hh < H;   // di >= 0, so only upper clip
        #pragma unroll
        for (int dj = (di == 0 ? 1 : -R); dj <= R; ++dj) {
            const int ww = w + dj;
            if (rowok && (unsigned)ww < (unsigned)W) {
                const int idx = hh * WD + ww * D + d0;
                const float4 sn4 = *(const float4*)(sb  + idx);
                const float4 a4  = *(const float4*)(y0b + idx);
                const float A = -0.5f * (float)(di * di + dj * dj) *
                                (INV_SXY * INV_SXY);
                const float snv[4] = {sn4.x, sn4.y, sn4.z, sn4.w};
                const float av[4]  = {a4.x,  a4.y,  a4.z,  a4.w};
                #pragma unroll
                for (int j = 0; j < 4; ++j) {
                    const float dsr = snv[j] - scv[j];
                    const float k = __expf(A - 0.5f * (INV_SIMG * INV_SIMG) *
                                                   dsr * dsr);
                    // 1 - <y_n,y_c> = a + b - 2ab
                    const float t = av[j] + bv[j] - 2.0f * av[j] * bv[j];
                    acc[j] += k * t;
                }
            }
        }
    }

    float part = 2.0f * (acc[0] + acc[1] + acc[2] + acc[3]);

    // OOB count over the FULL 7x7 window (center excluded): 49 - nrows*ncols
    const int nrows = min(h + R, H - 1) - max(h - R, 0) + 1;
    const int ncols = min(w + R, W - 1) - max(w - R, 0) + 1;
    const int oob = 49 - nrows * ncols;
    if (oob) {
        const float fh = (float)h * INV_SXY;
        const float fw = (float)w * INV_SXY;
        const float base = fh * fh + fw * fw;
        float koob = 0.0f;
        #pragma unroll
        for (int j = 0; j < 4; ++j) {
            const float fs = scv[j] * INV_SIMG;
            koob += __expf(-0.5f * (base + fs * fs));
        }
        part += (float)oob * koob;
    }

    #pragma unroll
    for (int off = 32; off; off >>= 1)
        part += __shfl_down(part, off, 64);

    __shared__ float wsum[4];
    if ((tid & 63) == 0) wsum[tid >> 6] = part;
    __syncthreads();
    if (tid == 0) partial[bid] = wsum[0] + wsum[1] + wsum[2] + wsum[3];
}

__global__ __launch_bounds__(256) void reduce_partials(
    const float* __restrict__ partial, float* __restrict__ out) {
    const int tid = threadIdx.x;
    float v = partial[tid] + partial[tid + 256];   // NBLOCKS = 512
    #pragma unroll
    for (int off = 32; off; off >>= 1)
        v += __shfl_down(v, off, 64);
    __shared__ float wsum[4];
    if ((tid & 63) == 0) wsum[tid >> 6] = v;
    __syncthreads();
    if (tid == 0)
        out[0] = (wsum[0] + wsum[1] + wsum[2] + wsum[3]) *
                 (1.0f / (float)(N * D * H * W));
}

extern "C" void kernel_launch(void* const* d_in, const int* in_sizes, int n_in,
                              void* d_out, int out_size, void* d_ws, size_t ws_size,
                              hipStream_t stream) {
    const float* y = (const float*)d_in[0];
    const float* s = (const float*)d_in[1];
    float* partial = (float*)d_ws;   // 512 floats, all written before read

    crf_partial<<<dim3(NBLOCKS), dim3(256), 0, stream>>>(y, s, partial);
    reduce_partials<<<dim3(1), dim3(256), 0, stream>>>(partial, (float*)d_out);
}

// Round 5
// 64.072 us; speedup vs baseline: 1.4994x; 1.0186x over previous
//
#include <hip/hip_runtime.h>

// Gated CRF 3D->2D loss, round 5 (= R4 with the exp2 builtin fixed).
// Split half-window across 2 block groups: 1024 blocks (4/CU) for latency
// hiding; group g handles 12 of the 24 symmetric pair offsets.
// exp2-domain via __builtin_amdgcn_exp2f (v_exp_f32). Pair symmetry + C=2
// softmax identity (y1 = 1-y0):
//   loss = [ 2*sum_pairs k*(a+b-2ab) + sum_c oob(h,w)*exp(-0.5|f_c|^2) ]/denom

constexpr int N = 2, H = 64, W = 64, D = 64, R = 3;
constexpr int WD  = W * D;
constexpr int HWD = H * W * D;
constexpr float INV_SXY  = 1.0f / 6.0f;
constexpr float LOG2E    = 1.4426950408889634f;
constexpr float C2       = 50.0f * LOG2E;   // 0.5*(1/0.1)^2 * log2(e)
constexpr int GBLOCKS = N * H * (W / 16);   // 512 spatial blocks
constexpr int NBLOCKS = 2 * GBLOCKS;        // x2 offset groups = 1024

__device__ __forceinline__ float exp2_fast(float x) {
    return __builtin_amdgcn_exp2f(x);       // v_exp_f32
}

__global__ __launch_bounds__(256) void crf_partial(
    const float* __restrict__ y,   // (N,2,H,W,D) -- only channel 0 read
    const float* __restrict__ s,   // (N,1,H,W,D)
    float* __restrict__ partial) {
    const int tid   = threadIdx.x;
    const int d0    = (tid & 15) << 2;
    const int wlane = tid >> 4;
    const int bid   = blockIdx.x;
    const int sbid  = bid & (GBLOCKS - 1);
    const int g     = bid >> 9;            // offset group 0/1
    const int w = ((sbid & 3) << 4) + wlane;
    const int h = (sbid >> 2) & 63;
    const int n = sbid >> 8;

    const float* sb  = s + (size_t)n * HWD;
    const float* y0b = y + (size_t)n * (2 * HWD);

    const int cidx = h * WD + w * D + d0;
    const float4 sc4 = *(const float4*)(sb  + cidx);
    const float4 b4  = *(const float4*)(y0b + cidx);
    const float scv[4] = {sc4.x, sc4.y, sc4.z, sc4.w};
    const float bv[4]  = {b4.x,  b4.y,  b4.z,  b4.w};

    float acc[4] = {0.f, 0.f, 0.f, 0.f};

    #define PAIR(di, dj)                                                      \
    {                                                                         \
        const int hh = h + (di);                                              \
        const int ww = w + (dj);                                              \
        if (hh < H && (unsigned)ww < (unsigned)W) {                           \
            const int idx = hh * WD + ww * D + d0;                            \
            const float4 sn4 = *(const float4*)(sb  + idx);                   \
            const float4 a4  = *(const float4*)(y0b + idx);                   \
            const float A2 = -0.5f * (float)((di)*(di) + (dj)*(dj)) *         \
                             (INV_SXY * INV_SXY) * LOG2E;                     \
            const float snv[4] = {sn4.x, sn4.y, sn4.z, sn4.w};                \
            const float av[4]  = {a4.x,  a4.y,  a4.z,  a4.w};                 \
            _Pragma("unroll")                                                 \
            for (int j = 0; j < 4; ++j) {                                     \
                const float dsr = snv[j] - scv[j];                            \
                const float k = exp2_fast(A2 - C2 * dsr * dsr);               \
                acc[j] += k * (av[j] + bv[j] - 2.0f * av[j] * bv[j]);         \
            }                                                                 \
        }                                                                     \
    }

    float extra = 0.0f;
    if (g == 0) {
        PAIR(0, 1) PAIR(0, 2) PAIR(0, 3)
        PAIR(1, -3) PAIR(1, -2) PAIR(1, -1) PAIR(1, 0)
        PAIR(1, 1) PAIR(1, 2) PAIR(1, 3)
        PAIR(2, -3) PAIR(2, -2)
        const int nrows = min(h + R, H - 1) - max(h - R, 0) + 1;
        const int ncols = min(w + R, W - 1) - max(w - R, 0) + 1;
        const int oob = 49 - nrows * ncols;
        if (oob) {
            const float fh = (float)h * INV_SXY;
            const float fw = (float)w * INV_SXY;
            const float base2 = -0.5f * (fh * fh + fw * fw) * LOG2E;
            float koob = 0.0f;
            #pragma unroll
            for (int j = 0; j < 4; ++j)
                koob += exp2_fast(base2 - C2 * scv[j] * scv[j]);
            extra = (float)oob * koob;
        }
    } else {
        PAIR(2, -1) PAIR(2, 0) PAIR(2, 1) PAIR(2, 2) PAIR(2, 3)
        PAIR(3, -3) PAIR(3, -2) PAIR(3, -1) PAIR(3, 0)
        PAIR(3, 1) PAIR(3, 2) PAIR(3, 3)
    }
    #undef PAIR

    float part = 2.0f * (acc[0] + acc[1] + acc[2] + acc[3]) + extra;

    #pragma unroll
    for (int off = 32; off; off >>= 1)
        part += __shfl_down(part, off, 64);

    __shared__ float wsum[4];
    if ((tid & 63) == 0) wsum[tid >> 6] = part;
    __syncthreads();
    if (tid == 0) partial[bid] = wsum[0] + wsum[1] + wsum[2] + wsum[3];
}

__global__ __launch_bounds__(256) void reduce_partials(
    const float* __restrict__ partial, float* __restrict__ out) {
    const int tid = threadIdx.x;
    float v = 0.0f;
    #pragma unroll
    for (int i = 0; i < NBLOCKS / 256; ++i)
        v += partial[tid + i * 256];
    #pragma unroll
    for (int off = 32; off; off >>= 1)
        v += __shfl_down(v, off, 64);
    __shared__ float wsum[4];
    if ((tid & 63) == 0) wsum[tid >> 6] = v;
    __syncthreads();
    if (tid == 0)
        out[0] = (wsum[0] + wsum[1] + wsum[2] + wsum[3]) *
                 (1.0f / (float)(N * D * H * W));
}

extern "C" void kernel_launch(void* const* d_in, const int* in_sizes, int n_in,
                              void* d_out, int out_size, void* d_ws, size_t ws_size,
                              hipStream_t stream) {
    const float* y = (const float*)d_in[0];
    const float* s = (const float*)d_in[1];
    float* partial = (float*)d_ws;   // NBLOCKS floats, all written before read

    crf_partial<<<dim3(NBLOCKS), dim3(256), 0, stream>>>(y, s, partial);
    reduce_partials<<<dim3(1), dim3(256), 0, stream>>>(partial, (float*)d_out);
}

// Round 6
// 63.094 us; speedup vs baseline: 1.5227x; 1.0155x over previous
//
#include <hip/hip_runtime.h>

// Gated CRF 3D->2D loss, round 6: 4-way offset split.
// 2048 blocks (8/CU, 32 waves/CU): group g in 0..3 handles 6 of the 24
// symmetric pair offsets -> max TLP for the latency-bound gather loop.
// Pair symmetry + C=2 softmax identity (y1 = 1-y0), exp2-domain via
// __builtin_amdgcn_exp2f:
//   loss = [ 2*sum_pairs k*(a+b-2ab) + sum_c oob(h,w)*exp(-0.5|f_c|^2) ]/denom
// OOB closed form lives in group 0 only.

constexpr int N = 2, H = 64, W = 64, D = 64, R = 3;
constexpr int WD  = W * D;
constexpr int HWD = H * W * D;
constexpr float INV_SXY  = 1.0f / 6.0f;
constexpr float LOG2E    = 1.4426950408889634f;
constexpr float C2       = 50.0f * LOG2E;   // 0.5*(1/0.1)^2 * log2(e)
constexpr int GBLOCKS = N * H * (W / 16);   // 512 spatial blocks
constexpr int NBLOCKS = 4 * GBLOCKS;        // x4 offset groups = 2048

__device__ __forceinline__ float exp2_fast(float x) {
    return __builtin_amdgcn_exp2f(x);       // v_exp_f32
}

__global__ __launch_bounds__(256) void crf_partial(
    const float* __restrict__ y,   // (N,2,H,W,D) -- only channel 0 read
    const float* __restrict__ s,   // (N,1,H,W,D)
    float* __restrict__ partial) {
    const int tid   = threadIdx.x;
    const int d0    = (tid & 15) << 2;
    const int wlane = tid >> 4;
    const int bid   = blockIdx.x;
    const int sbid  = bid & (GBLOCKS - 1);
    const int g     = bid >> 9;            // offset group 0..3
    const int w = ((sbid & 3) << 4) + wlane;
    const int h = (sbid >> 2) & 63;
    const int n = sbid >> 8;

    const float* sb  = s + (size_t)n * HWD;
    const float* y0b = y + (size_t)n * (2 * HWD);

    const int cidx = h * WD + w * D + d0;
    const float4 sc4 = *(const float4*)(sb  + cidx);
    const float4 b4  = *(const float4*)(y0b + cidx);
    const float scv[4] = {sc4.x, sc4.y, sc4.z, sc4.w};
    const float bv[4]  = {b4.x,  b4.y,  b4.z,  b4.w};

    float acc[4] = {0.f, 0.f, 0.f, 0.f};

    #define PAIR(di, dj)                                                      \
    {                                                                         \
        const int hh = h + (di);                                              \
        const int ww = w + (dj);                                              \
        if (hh < H && (unsigned)ww < (unsigned)W) {                           \
            const int idx = hh * WD + ww * D + d0;                            \
            const float4 sn4 = *(const float4*)(sb  + idx);                   \
            const float4 a4  = *(const float4*)(y0b + idx);                   \
            const float A2 = -0.5f * (float)((di)*(di) + (dj)*(dj)) *         \
                             (INV_SXY * INV_SXY) * LOG2E;                     \
            const float snv[4] = {sn4.x, sn4.y, sn4.z, sn4.w};                \
            const float av[4]  = {a4.x,  a4.y,  a4.z,  a4.w};                 \
            _Pragma("unroll")                                                 \
            for (int j = 0; j < 4; ++j) {                                     \
                const float dsr = snv[j] - scv[j];                            \
                const float k = exp2_fast(A2 - C2 * dsr * dsr);               \
                acc[j] += k * (av[j] + bv[j] - 2.0f * av[j] * bv[j]);         \
            }                                                                 \
        }                                                                     \
    }

    float extra = 0.0f;
    if (g == 0) {
        PAIR(0, 1) PAIR(0, 2) PAIR(0, 3)
        PAIR(1, -3) PAIR(1, -2) PAIR(1, -1)
        const int nrows = min(h + R, H - 1) - max(h - R, 0) + 1;
        const int ncols = min(w + R, W - 1) - max(w - R, 0) + 1;
        const int oob = 49 - nrows * ncols;
        if (oob) {
            const float fh = (float)h * INV_SXY;
            const float fw = (float)w * INV_SXY;
            const float base2 = -0.5f * (fh * fh + fw * fw) * LOG2E;
            float koob = 0.0f;
            #pragma unroll
            for (int j = 0; j < 4; ++j)
                koob += exp2_fast(base2 - C2 * scv[j] * scv[j]);
            extra = (float)oob * koob;
        }
    } else if (g == 1) {
        PAIR(1, 0) PAIR(1, 1) PAIR(1, 2) PAIR(1, 3)
        PAIR(2, -3) PAIR(2, -2)
    } else if (g == 2) {
        PAIR(2, -1) PAIR(2, 0) PAIR(2, 1) PAIR(2, 2) PAIR(2, 3)
        PAIR(3, -3)
    } else {
        PAIR(3, -2) PAIR(3, -1) PAIR(3, 0)
        PAIR(3, 1) PAIR(3, 2) PAIR(3, 3)
    }
    #undef PAIR

    float part = 2.0f * (acc[0] + acc[1] + acc[2] + acc[3]) + extra;

    #pragma unroll
    for (int off = 32; off; off >>= 1)
        part += __shfl_down(part, off, 64);

    __shared__ float wsum[4];
    if ((tid & 63) == 0) wsum[tid >> 6] = part;
    __syncthreads();
    if (tid == 0) partial[bid] = wsum[0] + wsum[1] + wsum[2] + wsum[3];
}

__global__ __launch_bounds__(256) void reduce_partials(
    const float* __restrict__ partial, float* __restrict__ out) {
    const int tid = threadIdx.x;
    float v = 0.0f;
    #pragma unroll
    for (int i = 0; i < NBLOCKS / 256; ++i)
        v += partial[tid + i * 256];
    #pragma unroll
    for (int off = 32; off; off >>= 1)
        v += __shfl_down(v, off, 64);
    __shared__ float wsum[4];
    if ((tid & 63) == 0) wsum[tid >> 6] = v;
    __syncthreads();
    if (tid == 0)
        out[0] = (wsum[0] + wsum[1] + wsum[2] + wsum[3]) *
                 (1.0f / (float)(N * D * H * W));
}

extern "C" void kernel_launch(void* const* d_in, const int* in_sizes, int n_in,
                              void* d_out, int out_size, void* d_ws, size_t ws_size,
                              hipStream_t stream) {
    const float* y = (const float*)d_in[0];
    const float* s = (const float*)d_in[1];
    float* partial = (float*)d_ws;   // NBLOCKS floats, all written before read

    crf_partial<<<dim3(NBLOCKS), dim3(256), 0, stream>>>(y, s, partial);
    reduce_partials<<<dim3(1), dim3(256), 0, stream>>>(partial, (float*)d_out);
}